// Round 5
// baseline (448.288 us; speedup 1.0000x reference)
//
#include <hip/hip_runtime.h>
#include <math.h>

#define N_NODES 50000
#define N_EDGES 800000
#define N_GRAPHS 512
#define SLOPE 0.2f
#define CAP 48   // bucket capacity; degrees ~Binomial(800k,1/50k)~Poisson(16), P(deg>48)~1e-11
static constexpr float EPS_BN = 1e-5f;
static constexpr unsigned MAXOFF = (N_NODES - 1) * 64;  // clamp for garbage-slot gathers

typedef float v2f __attribute__((ext_vector_type(2)));

// ---------------- fused bucket-scatter + layer-0 transform (known-good t9) ----------
// Record = {float_bits(src*64), e0, e1, e2} : 16B, ea embedded, src pre-scaled to
// element offset so gat can use 32-bit saddr addressing (1 VALU per gather address).
// NOTE (R3): EPT=4 variant regressed (occupancy 64%->28%; 200k threads < machine
// capacity). This kernel is TLP-bound: keep 1 edge/thread, 800k threads.
// ~57 us is the atomic-chain floor at max TLP (tested EPT 1/2/4); accepted.

__global__ __launch_bounds__(256) void scatter_t9_kernel(
    const int* __restrict__ src, const int* __restrict__ dst,
    const float* __restrict__ ea,
    int* __restrict__ cnt, float4* __restrict__ rec,
    const float* __restrict__ x,
    const float* __restrict__ Wl0, const float* __restrict__ bl0,
    const float* __restrict__ Wr0, const float* __restrict__ br0,
    float* __restrict__ xl, float* __restrict__ xr) {
    int t = threadIdx.x;
    int e = blockIdx.x * 256 + t;
    if (e < N_EDGES) {
        int d = dst[e];
        int pos = atomicAdd(&cnt[d], 1);
        if (pos < CAP)
            rec[(size_t)d * CAP + pos] = make_float4(__int_as_float(src[e] * 64),
                                                     ea[e * 3 + 0], ea[e * 3 + 1], ea[e * 3 + 2]);
    }

    // layer-0 transform: grid-stride waves, 4 nodes/block-pass
    int w = t >> 6;
    int k = t & 63;
    v2f wlr[9];
#pragma unroll
    for (int j = 0; j < 9; j++) wlr[j] = (v2f){Wl0[j * 64 + k], Wr0[j * 64 + k]};
    v2f bias = {bl0[k], br0[k]};
    const int NW = gridDim.x * 4;
    for (int n = blockIdx.x * 4 + w; n < N_NODES; n += NW) {
        int un = __builtin_amdgcn_readfirstlane(n);
        const float* __restrict__ hrow = x + (size_t)un * 9;
        float hb[9];
#pragma unroll
        for (int j = 0; j < 9; j++) hb[j] = hrow[j];
        v2f acc = bias;
#pragma unroll
        for (int j = 0; j < 9; j++)
            acc = __builtin_elementwise_fma((v2f){hb[j], hb[j]}, wlr[j], acc);
        xl[(size_t)un * 64 + k] = acc.x;
        xr[(size_t)un * 64 + k] = acc.y;
    }
}

// ---------------- main transform (K=64): LDS-tiled GEMM (round-2 known-good) ------

__global__ __launch_bounds__(256) void transform6_kernel(
    const float* __restrict__ h,
    const float* __restrict__ Wl, const float* __restrict__ bl,
    const float* __restrict__ Wr, const float* __restrict__ br,
    float* __restrict__ xl, float* __restrict__ xr) {
    __shared__ float sAt[64][68];
    __shared__ float sB[64][128];
    int t = threadIdx.x;
    int n0 = blockIdx.x * 64;

#pragma unroll
    for (int i = 0; i < 4; i++) {
        int idx = i * 256 + t;
        int row = idx >> 4;
        int fc  = idx & 15;
        int n = n0 + row;
        float4 v = (n < N_NODES) ? *((const float4*)(h + (size_t)n * 64 + fc * 4))
                                 : make_float4(0.f, 0.f, 0.f, 0.f);
        sAt[fc * 4 + 0][row] = v.x;
        sAt[fc * 4 + 1][row] = v.y;
        sAt[fc * 4 + 2][row] = v.z;
        sAt[fc * 4 + 3][row] = v.w;
    }
#pragma unroll
    for (int i = 0; i < 8; i++) {
        int idx = i * 256 + t;
        int j  = idx >> 5;
        int fc = idx & 31;
        int c  = fc * 4;
        float4 v = (c < 64) ? *((const float4*)(Wl + j * 64 + c))
                            : *((const float4*)(Wr + j * 64 + (c - 64)));
        *((float4*)&sB[j][c]) = v;
    }
    __syncthreads();

    int tx = t & 15, ty = t >> 4;
    int c0 = tx * 4;
    float4 bls = *((const float4*)(bl + c0));
    float4 brs = *((const float4*)(br + c0));
    v2f acc[4][4];
#pragma unroll
    for (int r = 0; r < 4; r++) {
        acc[r][0] = (v2f){bls.x, bls.y};
        acc[r][1] = (v2f){bls.z, bls.w};
        acc[r][2] = (v2f){brs.x, brs.y};
        acc[r][3] = (v2f){brs.z, brs.w};
    }

#pragma unroll 4
    for (int j = 0; j < 64; j++) {
        float a0 = sAt[j][ty * 4 + 0];
        float a1 = sAt[j][ty * 4 + 1];
        float a2 = sAt[j][ty * 4 + 2];
        float a3 = sAt[j][ty * 4 + 3];
        float4 bq0 = *((const float4*)&sB[j][c0]);        // Wl cols c0..c0+3
        float4 bq1 = *((const float4*)&sB[j][64 + c0]);   // Wr cols c0..c0+3
        v2f b0 = {bq0.x, bq0.y}, b1 = {bq0.z, bq0.w};
        v2f b2 = {bq1.x, bq1.y}, b3 = {bq1.z, bq1.w};
        v2f a0v = {a0, a0}, a1v = {a1, a1}, a2v = {a2, a2}, a3v = {a3, a3};
        acc[0][0] = __builtin_elementwise_fma(a0v, b0, acc[0][0]);
        acc[0][1] = __builtin_elementwise_fma(a0v, b1, acc[0][1]);
        acc[0][2] = __builtin_elementwise_fma(a0v, b2, acc[0][2]);
        acc[0][3] = __builtin_elementwise_fma(a0v, b3, acc[0][3]);
        acc[1][0] = __builtin_elementwise_fma(a1v, b0, acc[1][0]);
        acc[1][1] = __builtin_elementwise_fma(a1v, b1, acc[1][1]);
        acc[1][2] = __builtin_elementwise_fma(a1v, b2, acc[1][2]);
        acc[1][3] = __builtin_elementwise_fma(a1v, b3, acc[1][3]);
        acc[2][0] = __builtin_elementwise_fma(a2v, b0, acc[2][0]);
        acc[2][1] = __builtin_elementwise_fma(a2v, b1, acc[2][1]);
        acc[2][2] = __builtin_elementwise_fma(a2v, b2, acc[2][2]);
        acc[2][3] = __builtin_elementwise_fma(a2v, b3, acc[2][3]);
        acc[3][0] = __builtin_elementwise_fma(a3v, b0, acc[3][0]);
        acc[3][1] = __builtin_elementwise_fma(a3v, b1, acc[3][1]);
        acc[3][2] = __builtin_elementwise_fma(a3v, b2, acc[3][2]);
        acc[3][3] = __builtin_elementwise_fma(a3v, b3, acc[3][3]);
    }

#pragma unroll
    for (int r = 0; r < 4; r++) {
        int n = n0 + ty * 4 + r;
        if (n < N_NODES) {
            *((float4*)(xl + (size_t)n * 64 + c0)) =
                make_float4(acc[r][0].x, acc[r][0].y, acc[r][1].x, acc[r][1].y);
            *((float4*)(xr + (size_t)n * 64 + c0)) =
                make_float4(acc[r][2].x, acc[r][2].y, acc[r][3].x, acc[r][3].y);
        }
    }
}

// ---------------- fused GATv2 layer: 2-deep edge pipeline + cross-node prefetch ----
// Steady state per node: cnt + rec0 were prefetched during the PREVIOUS node, so the
// only serial latency left is gather0. Slots 0..7 are loaded unguarded (cnt unknown
// at prefetch time); garbage offsets are clamped to [0, MAXOFF] and their lanes are
// masked by pe=0 (select, not multiply -> no NaN path). This also fixes gat11's
// latent unguarded gather for cnt<1 nodes.

#define EDGE_T(rX, xXa, xXb, accX)                                        \
    {                                                                     \
        v2f tXa = xXa + xra, tXb = xXb + xrb;                             \
        tXa = __builtin_elementwise_fma((v2f){rX.y, rX.y}, we0a, tXa);    \
        tXb = __builtin_elementwise_fma((v2f){rX.y, rX.y}, we0b, tXb);    \
        tXa = __builtin_elementwise_fma((v2f){rX.z, rX.z}, we1a, tXa);    \
        tXb = __builtin_elementwise_fma((v2f){rX.z, rX.z}, we1b, tXb);    \
        tXa = __builtin_elementwise_fma((v2f){rX.w, rX.w}, we2a, tXa);    \
        tXb = __builtin_elementwise_fma((v2f){rX.w, rX.w}, we2b, tXb);    \
        tXa = __builtin_elementwise_max(tXa, tXa * SLOPE);                \
        tXb = __builtin_elementwise_max(tXb, tXb * SLOPE);                \
        v2f dX = ata * tXa;                                               \
        dX = __builtin_elementwise_fma(atb, tXb, dX);                     \
        accX = dX.x + dX.y;                                               \
    }

__global__ __launch_bounds__(256) void gat_fused12_kernel(
    const float* __restrict__ xl, const float* __restrict__ xr,
    const float4* __restrict__ recP, const int* __restrict__ cnt,
    const float* __restrict__ We, const float* __restrict__ att,
    const float* __restrict__ bo,
    const float* __restrict__ bn_g, const float* __restrict__ bn_b,
    const float* __restrict__ bn_m, const float* __restrict__ bn_v,
    float* __restrict__ hout) {
    int t = threadIdx.x;
    int w = t >> 6;
    int lane = t & 63;
    int q = lane >> 4;
    int r = lane & 15;
    int k4 = r * 4;

    // layer-invariant constants (hoisted out of the node loop)
    float4 we0 = *(const float4*)(We + 0 * 64 + k4);
    float4 we1 = *(const float4*)(We + 64 + k4);
    float4 we2 = *(const float4*)(We + 128 + k4);
    float4 at4 = *(const float4*)(att + k4);
    v2f we0a = {we0.x, we0.y}, we0b = {we0.z, we0.w};
    v2f we1a = {we1.x, we1.y}, we1b = {we1.z, we1.w};
    v2f we2a = {we2.x, we2.y}, we2b = {we2.z, we2.w};
    v2f ata  = {at4.x, at4.y}, atb  = {at4.z, at4.w};
    // fold bias+BN into res = max(o*zi*S + C, 0)
    float4 bo4 = *(const float4*)(bo + k4);
    float4 g4  = *(const float4*)(bn_g + k4);
    float4 b4  = *(const float4*)(bn_b + k4);
    float4 m4  = *(const float4*)(bn_m + k4);
    float4 v4  = *(const float4*)(bn_v + k4);
    float4 S, C;
    S.x = g4.x / sqrtf(v4.x + EPS_BN);  C.x = (bo4.x - m4.x) * S.x + b4.x;
    S.y = g4.y / sqrtf(v4.y + EPS_BN);  C.y = (bo4.y - m4.y) * S.y + b4.y;
    S.z = g4.z / sqrtf(v4.z + EPS_BN);  C.z = (bo4.z - m4.z) * S.z + b4.z;
    S.w = g4.w / sqrtf(v4.w + EPS_BN);  C.w = (bo4.w - m4.w) * S.w + b4.w;

    const int NW = gridDim.x * 4;
    int n0 = blockIdx.x * 4 + w;
    if (n0 >= N_NODES) return;

    // node-pipeline state: cnt + rec0 + xq for the CURRENT node (first node: cold)
    int nU = __builtin_amdgcn_readfirstlane(n0);
    int cn = cnt[nU];
    float4 rA0 = recP[nU * CAP + q];          // unguarded slots 0..7
    float4 rB0 = recP[nU * CAP + 4 + q];
    float4 xq = *(const float4*)(xr + (size_t)nU * 64 + k4);

    while (true) {
        int n = nU;
        int beg = n * CAP;
        int end = beg + min(cn, CAP);
        v2f xra = {xq.x, xq.y}, xrb = {xq.z, xq.w};

        // gathers for slots 0..7 (rec0 arrived a full node ago; clamp garbage)
        unsigned oA0 = min((unsigned)__float_as_int(rA0.x), MAXOFF) + k4;
        unsigned oB0 = min((unsigned)__float_as_int(rB0.x), MAXOFF) + k4;
        float4 gA0 = *(const float4*)(xl + oA0);
        float4 gB0 = *(const float4*)(xl + oB0);

        // rec loads for slots 8..15 (end known -> guarded)
        int pA1 = beg + 8 + q;  bool wA1 = pA1 < end;
        int pB1 = beg + 12 + q; bool wB1 = pB1 < end;
        float4 cA1 = recP[wA1 ? pA1 : beg];
        float4 cB1 = recP[wB1 ? pB1 : beg];

        // prefetch NEXT node's cnt + rec0 (independent of current node; rides out
        // the entire edge loop)
        int n1 = n0 + NW;
        bool hasNext = n1 < N_NODES;
        int nN = __builtin_amdgcn_readfirstlane(hasNext ? n1 : n0);
        int cnN = cnt[nN];
        float4 rA0N = recP[nN * CAP + q];
        float4 rB0N = recP[nN * CAP + 4 + q];

        v2f oAa = {0.f, 0.f}, oAb = {0.f, 0.f};
        v2f oBa = {0.f, 0.f}, oBb = {0.f, 0.f};
        float zA = 0.f, zB = 0.f;

        float4 cA0 = rA0, cB0 = rB0;
        bool wA0 = (beg + q) < end;
        bool wB0 = (beg + 4 + q) < end;

        int c = beg;
        while (c < end) {
            // gathers for iteration i+1 (clamped)
            unsigned oA1 = min((unsigned)__float_as_int(cA1.x), MAXOFF) + k4;
            unsigned oB1 = min((unsigned)__float_as_int(cB1.x), MAXOFF) + k4;
            float4 gA1 = *(const float4*)(xl + oA1);
            float4 gB1 = *(const float4*)(xl + oB1);
            // rec loads for iteration i+2 (guarded)
            int c2 = c + 16;
            int pA2 = c2 + q;     bool wA2 = pA2 < end;
            int pB2 = c2 + 4 + q; bool wB2 = pB2 < end;
            float4 cA2 = recP[wA2 ? pA2 : beg];
            float4 cB2 = recP[wB2 ? pB2 : beg];

            // compute iteration i
            v2f xAa = {gA0.x, gA0.y}, xAb = {gA0.z, gA0.w};
            v2f xBa = {gB0.x, gB0.y}, xBb = {gB0.z, gB0.w};

            float accA, accB;
            EDGE_T(cA0, xAa, xAb, accA);
            EDGE_T(cB0, xBa, xBb, accB);

            accA += __shfl_xor(accA, 1, 64);  accB += __shfl_xor(accB, 1, 64);
            accA += __shfl_xor(accA, 2, 64);  accB += __shfl_xor(accB, 2, 64);
            accA += __shfl_xor(accA, 4, 64);  accB += __shfl_xor(accB, 4, 64);
            accA += __shfl_xor(accA, 8, 64);  accB += __shfl_xor(accB, 8, 64);

            float peA = wA0 ? __expf(accA) : 0.f;
            float peB = wB0 ? __expf(accB) : 0.f;
            v2f pAv = {peA, peA}, pBv = {peB, peB};
            oAa = __builtin_elementwise_fma(pAv, xAa, oAa);
            oAb = __builtin_elementwise_fma(pAv, xAb, oAb);
            oBa = __builtin_elementwise_fma(pBv, xBa, oBa);
            oBb = __builtin_elementwise_fma(pBv, xBb, oBb);
            zA += peA; zB += peB;

            // rotate pipeline
            cA0 = cA1; cB0 = cB1; wA0 = wA1; wB0 = wB1;
            cA1 = cA2; cB1 = cB2; wA1 = wA2; wB1 = wB2;
            gA0 = gA1; gB0 = gB1;
            c += 8;
        }

        v2f oa = oAa + oBa, ob = oAb + oBb;
        float z = zA + zB;
        float4 o = make_float4(oa.x, oa.y, ob.x, ob.y);
        o.x += __shfl_xor(o.x, 16, 64); o.x += __shfl_xor(o.x, 32, 64);
        o.y += __shfl_xor(o.y, 16, 64); o.y += __shfl_xor(o.y, 32, 64);
        o.z += __shfl_xor(o.z, 16, 64); o.z += __shfl_xor(o.z, 32, 64);
        o.w += __shfl_xor(o.w, 16, 64); o.w += __shfl_xor(o.w, 32, 64);
        z += __shfl_xor(z, 16, 64); z += __shfl_xor(z, 32, 64);

        if (q == 0) {
            float zi = 1.0f / fmaxf(z, 1e-16f);
            float4 res;
            res.x = fmaxf(fmaf(o.x * zi, S.x, C.x), 0.f);
            res.y = fmaxf(fmaf(o.y * zi, S.y, C.y), 0.f);
            res.z = fmaxf(fmaf(o.z * zi, S.z, C.z), 0.f);
            res.w = fmaxf(fmaf(o.w * zi, S.w, C.w), 0.f);
            *(float4*)(hout + (size_t)n * 64 + k4) = res;
        }

        if (!hasNext) break;
        // rotate node pipeline; xq load here hides under next node's gather0 wait
        n0 = n1; nU = nN; cn = cnN; rA0 = rA0N; rB0 = rB0N;
        xq = *(const float4*)(xr + (size_t)nU * 64 + k4);
    }
}

// ---------------- readout: 4 waves/block, LDS cross-wave reduce ----------------

__global__ __launch_bounds__(256) void pool_all2_kernel(
    const float* __restrict__ h, const int* __restrict__ batch,
    const float* __restrict__ Wjk, const float* __restrict__ bjk,
    const float* __restrict__ Whead, const float* __restrict__ bhead,
    float* __restrict__ out) {
    __shared__ float red[4][64];
    int g = blockIdx.x;
    int t = threadIdx.x;
    int k = t & 63;
    int w = t >> 6;
    int lo = 0, hi = N_NODES;
    while (lo < hi) { int mid = (lo + hi) >> 1; if (batch[mid] < g) lo = mid + 1; else hi = mid; }
    int s = lo;
    hi = N_NODES;
    while (lo < hi) { int mid = (lo + hi) >> 1; if (batch[mid] < g + 1) lo = mid + 1; else hi = mid; }
    int e = lo;

    float acc = 0.f;
    for (int n = s + w; n < e; n += 4) acc += h[(size_t)n * 64 + k];
    red[w][k] = acc;
    __syncthreads();

    if (w == 0) {
        acc = (red[0][k] + red[1][k]) + (red[2][k] + red[3][k]);
        float wc = 0.f;
        for (int j = 0; j < 64; j++) wc = fmaf(Wjk[k * 64 + j], Whead[j], wc);
        float bc = bjk[k] * Whead[k];
        for (int off = 32; off > 0; off >>= 1) bc += __shfl_xor(bc, off, 64);
        float cntf = (float)(e - s);
        acc /= fmaxf(cntf, 1.0f);
        float v = acc * wc;
        for (int off = 32; off > 0; off >>= 1) v += __shfl_xor(v, off, 64);
        if (k == 0) out[g] = v + bc + bhead[0];
    }
}

// ---------------- launch ----------------

extern "C" void kernel_launch(void* const* d_in, const int* in_sizes, int n_in,
                              void* d_out, int out_size, void* d_ws, size_t ws_size,
                              hipStream_t stream) {
    const float* x     = (const float*)d_in[0];
    const float* ea    = (const float*)d_in[1];
    const float* Wl0   = (const float*)d_in[2];
    const float* Wr0   = (const float*)d_in[3];
    const float* bl0   = (const float*)d_in[4];
    const float* br0   = (const float*)d_in[5];
    const float* We0   = (const float*)d_in[6];
    const float* att0  = (const float*)d_in[7];
    const float* bo0   = (const float*)d_in[8];
    const float* Wl    = (const float*)d_in[9];
    const float* Wr    = (const float*)d_in[10];
    const float* bl    = (const float*)d_in[11];
    const float* br    = (const float*)d_in[12];
    const float* We    = (const float*)d_in[13];
    const float* att   = (const float*)d_in[14];
    const float* bo    = (const float*)d_in[15];
    const float* bn_g  = (const float*)d_in[16];
    const float* bn_b  = (const float*)d_in[17];
    const float* bn_m  = (const float*)d_in[18];
    const float* bn_v  = (const float*)d_in[19];
    const float* Wjk   = (const float*)d_in[20];
    const float* bjk   = (const float*)d_in[21];
    const float* Whead = (const float*)d_in[22];
    const float* bhead = (const float*)d_in[23];
    const int* edge_index = (const int*)d_in[24];
    const int* batch      = (const int*)d_in[25];

    const int* srcIdx = edge_index;            // edge_index[0]
    const int* dstIdx = edge_index + N_EDGES;  // edge_index[1]

    char* ws = (char*)d_ws;
    size_t off = 0;
    auto alloc = [&](size_t bytes) -> void* {
        void* p = ws + off;
        off += (bytes + 255) & ~(size_t)255;
        return p;
    };
    float* hA      = (float*)alloc((size_t)N_NODES * 64 * 4);
    float* hB      = (float*)alloc((size_t)N_NODES * 64 * 4);
    float* xlb     = (float*)alloc((size_t)N_NODES * 64 * 4);
    float* xrb     = (float*)alloc((size_t)N_NODES * 64 * 4);
    int*   cnt     = (int*)alloc((size_t)N_NODES * 4);
    float4* recP   = (float4*)alloc((size_t)N_NODES * CAP * 16);  // 38.4 MB

    // ---- fused bucket build + layer-0 transform ----
    hipMemsetAsync(cnt, 0, (size_t)N_NODES * 4, stream);
    scatter_t9_kernel<<<(N_EDGES + 255) / 256, 256, 0, stream>>>(
        srcIdx, dstIdx, ea, cnt, recP, x, Wl0, bl0, Wr0, br0, xlb, xrb);

    const int GB  = 2048;                      // gat grid: grid-stride, ~6 nodes/wave
    const int NBG = (N_NODES + 63) / 64;       // 782 (GEMM transform grid)

    // ---- layer 0 GAT ----
    gat_fused12_kernel<<<GB, 256, 0, stream>>>(xlb, xrb, recP, cnt,
                                               We0, att0, bo0,
                                               bn_g, bn_b, bn_m, bn_v, hA);

    // ---- layers 1..4 ----
    float* hcur = hA;
    float* hnext = hB;
    for (int i = 0; i < 4; i++) {
        transform6_kernel<<<NBG, 256, 0, stream>>>(hcur,
            Wl + (size_t)i * 64 * 64, bl + (size_t)i * 64,
            Wr + (size_t)i * 64 * 64, br + (size_t)i * 64,
            xlb, xrb);
        gat_fused12_kernel<<<GB, 256, 0, stream>>>(xlb, xrb, recP, cnt,
            We + (size_t)i * 3 * 64, att + (size_t)i * 64,
            bo + (size_t)i * 64,
            bn_g + (size_t)(i + 1) * 64, bn_b + (size_t)(i + 1) * 64,
            bn_m + (size_t)(i + 1) * 64, bn_v + (size_t)(i + 1) * 64,
            hnext);
        float* tp = hcur; hcur = hnext; hnext = tp;
    }

    // ---- readout ----
    pool_all2_kernel<<<N_GRAPHS, 256, 0, stream>>>(hcur, batch, Wjk, bjk, Whead, bhead,
                                                   (float*)d_out);
}